// Round 16
// baseline (835.315 us; speedup 1.0000x reference)
//
#include <hip/hip_runtime.h>
#include <hip/hip_bf16.h>
#include <stdint.h>

#define G_ 8
#define T_ 1024
#define K_ 7168
#define N_ 2048
#define KB_ 56         // K/128 quant blocks
#define NB_ 16         // N/128
#define NT8_ 56        // K-tiles of 128

#define ACT_WGS  57344   // (G*T*KB)/8

typedef __attribute__((ext_vector_type(4))) float f32x4;
typedef __attribute__((ext_vector_type(8))) int   i32x8;

typedef __attribute__((address_space(3))) uint32_t lds_u32_t;
typedef const __attribute__((address_space(1))) uint32_t gbl_u32_t;

__device__ __forceinline__ void gload_lds16(const void* gsrc, const void* ldst)
{
    __builtin_amdgcn_global_load_lds(
        (gbl_u32_t*)(uintptr_t)gsrc,
        (lds_u32_t*)(uint32_t)(uintptr_t)ldst, 16, 0, 0);
}

__device__ __forceinline__ void blockbar()
{
    asm volatile("" ::: "memory");
    __builtin_amdgcn_s_barrier();
    asm volatile("" ::: "memory");
}

// ---------------------------------------------------------------------------
// Kernel 1: activation quant only (weight recode now fused into GEMM
// producers). Verified body, rounds 6-15.
// ---------------------------------------------------------------------------
__global__ __launch_bounds__(256) void prep_kernel(
    const float* __restrict__ xs, uint8_t* __restrict__ xq8,
    float* __restrict__ ascale)
{
    const int bid = blockIdx.x;
    const int tid = threadIdx.x;
    const int grp = (bid * 256 + tid) >> 5;
    const int l   = tid & 31;
    const size_t base = (size_t)grp * 128 + (size_t)l * 4;

    const float4 v = *(const float4*)(xs + base);
    float am = fmaxf(fmaxf(fabsf(v.x), fabsf(v.y)),
                     fmaxf(fabsf(v.z), fabsf(v.w)));
#pragma unroll
    for (int off = 1; off <= 16; off <<= 1)
        am = fmaxf(am, __shfl_xor(am, off, 64));

    const float rs = 448.0f / am;
    const float s  = am * (1.0f / 448.0f);

    int pk = __builtin_amdgcn_cvt_pk_fp8_f32(v.x * rs, v.y * rs, 0, false);
    pk     = __builtin_amdgcn_cvt_pk_fp8_f32(v.z * rs, v.w * rs, pk, true);
    *(uint32_t*)(xq8 + base) = (uint32_t)pk;

    if (l == 0) {
        const int kb = grp % KB_;
        const int t  = (grp / KB_) & (T_ - 1);
        const int g  = grp / (KB_ * T_);
        ascale[(((size_t)(g * 4 + (t >> 8))) * KB_ + kb) * 256 + (t & 255)] = s;
    }
}

// ---------------------------------------------------------------------------
// Kernel 2: producer/consumer blockwise-fp8 grouped GEMM, 256x128 tile,
//   FUSED weight recode on producer waves.
//   768 threads, 1 block/CU. Waves 0-7: consumers (r15 body, unchanged).
//   Waves 8-11: producers — A fp8 via global_load_lds (ring-3), B fp32
//   codes via coalesced dwordx4 -> cvt_pk_fp8 -> swizzled ds_write_b32.
//   Ledger per interval u: issue A-DMA(u+2); vmcnt(8) (drains A(u+1) +
//   B-regs(u+1) + S, each with >=1 interval of flight); cvt+write B(u+1);
//   issue B-loads(u+2); [S]; lgkmcnt(0); barrier.
//   LDS: A 3x32K @0 | B 3x16K @98304 | ascale 2x4K @147456 | ws @155648.
// ---------------------------------------------------------------------------
union Frag { i32x8 v; struct { int4 lo, hi; } p; };

#define RD_FRAG(dst, base, r)                                                 \
  { const int rx_ = ((r) & 7) << 4;                                           \
    const char* bp_ = smem + (base) + (r)*128;                                \
    dst.p.lo = *(const int4*)(bp_ + ((lhi*32) ^ rx_));                        \
    dst.p.hi = *(const int4*)(bp_ + ((lhi*32 + 16) ^ rx_)); }

#define STG_A(c, t, bb) gload_lds16(pA8[c] + (size_t)(t)*128,                 \
      smem + (bb)*32768 + (c)*4096 + ptid*16)
#define STG_S(c) gload_lds16(pS + (size_t)(c)*1024,                           \
      smem + 147456 + ((c)&1)*4096 + ptid*16)

// 16 coalesced dwordx4 loads of fp32 codes for B k-tile t (flat layout:
// load q covers rows q*8..q*8+7; lane-contiguous 16B)
#define LOAD_B16(t)                                                           \
  { _Pragma("unroll") for (int q = 0; q < 16; ++q)                            \
      br[q] = *(const f32x4*)(pWf + (size_t)q * 8 * K_ + (size_t)(t) * 128); }

// convert + swizzled ds_write_b32 into B buf bb (matches consumer layout)
#define CVT_WRITE_B(bb)                                                       \
  { _Pragma("unroll") for (int q = 0; q < 16; ++q) {                          \
      int pk_ = __builtin_amdgcn_cvt_pk_fp8_f32(br[q][0], br[q][1], 0, false);\
      pk_ = __builtin_amdgcn_cvt_pk_fp8_f32(br[q][2], br[q][3], pk_, true);   \
      const int r_ = q * 8 + (ptid >> 5);                                     \
      *(uint32_t*)(smem + 98304 + (bb)*16384 + r_*128 +                       \
          ((((ptid & 31) >> 2) ^ (r_ & 7)) << 4) + (ptid & 3) * 4) =          \
          (uint32_t)pk_;                                                      \
  } }

__global__ __launch_bounds__(768, 1) void gemm_fp8_kernel(
    const uint8_t* __restrict__ xq8, const float* __restrict__ w,
    const float* __restrict__ ascale, const float* __restrict__ wscale,
    const float* __restrict__ bias, float* __restrict__ y)
{
    __shared__ char smem[155904];

    const int bx0 = blockIdx.x;          // 0..511
    const int g     = bx0 & 7;           // group == XCD
    const int inner = bx0 >> 3;          // 0..63
    const int tm    = inner & 3;         // 0..3 (256-row tiles)
    const int tn    = inner >> 2;        // 0..15
    const int t0 = tm * 256, n0 = tn * 128;

    const int tid  = threadIdx.x, lane = tid & 63, wid = tid >> 6;
    const bool producer = (wid >= 8);
    const int ptid = tid & 255;          // producer-local 0..255
    const int l15 = lane & 15, lhi = lane >> 4;
    const int wrow = (wid >> 1) * 64;    // consumer rows (wid 0..7)
    const int wcol = (wid & 1) * 64;

    const uint8_t* Ag = xq8 + (size_t)g * T_ * K_;
    const float*   Wg = w   + (size_t)g * N_ * K_;

    // A staging map: LDS(row = c*32 + ptid/8, slot = ptid&7) <- global
    // slot ^ (row&7)
    const int srow = ptid >> 3;
    const int xoff = ((ptid & 7) ^ (srow & 7)) * 16;
    const uint8_t* pA8[8];
#pragma unroll
    for (int c = 0; c < 8; ++c)
        pA8[c] = Ag + (size_t)(t0 + c * 32 + srow) * K_ + xoff;

    // B fp32 source: load q covers row q*8 + (ptid>>5), cols (ptid&31)*4..
    const float* pWf = Wg + (size_t)(n0 + (ptid >> 5)) * K_ + (ptid & 31) * 4;

    // ascale: [g][tb][kb][256], tb == tm; chunk = 4 kb = 4KB
    const float* pS = ascale + ((size_t)(g * 4 + tm) * KB_) * 256 + ptid * 4;

    const f32x4 z4 = {0.f, 0.f, 0.f, 0.f};
    f32x4 acc[4][4] = {};
    Frag bF[4];
    f32x4 asv[4];
    f32x4 br[16];

    // ---- prologue ----
    if (producer) {
        if (ptid < KB_) {
            const float wv = wscale[((size_t)(g * NB_ + tn)) * KB_ + ptid];
            *(float*)(smem + 155648 + ptid * 4) = wv;
        }
        STG_S(0);
#pragma unroll
        for (int c = 0; c < 8; ++c) STG_A(c, 0, 0);
        LOAD_B16(0);
        asm volatile("s_waitcnt vmcnt(0)" ::: "memory");   // S0+A0+B0 landed
        CVT_WRITE_B(0);
#pragma unroll
        for (int c = 0; c < 8; ++c) STG_A(c, 1, 1);
        LOAD_B16(1);
        asm volatile("s_waitcnt lgkmcnt(0)" ::: "memory"); // wscale+B0 writes
    } else {
        __builtin_amdgcn_s_setprio(1);   // consumers keep MFMA priority
    }
    blockbar();
    // entering u=0 in flight: A8(1), B16(1)

    int cur = 0;
    for (int u = 0; u < NT8_; ++u) {
        if (producer) {
            if (u + 2 < NT8_) {
                const int fb = (cur + 2 >= 3) ? cur - 1 : cur + 2;   // (u+2)%3
                const int nb = (cur + 1 >= 3) ? 0 : cur + 1;         // (u+1)%3
#pragma unroll
                for (int c = 0; c < 8; ++c) STG_A(c, u + 2, fb);
                // drain A(u+1)+B-regs(u+1)+S (1 interval flight); keep A(u+2)
                asm volatile("s_waitcnt vmcnt(8)" ::: "memory");
                CVT_WRITE_B(nb);                  // tile u+1 -> buf (u+1)%3
                LOAD_B16(u + 2);
                if ((u & 3) == 0 && u + 4 < NT8_) STG_S((u >> 2) + 1);
                asm volatile("s_waitcnt lgkmcnt(0)" ::: "memory");
            } else if (u + 1 < NT8_) {
                const int nb = (cur + 1 >= 3) ? 0 : cur + 1;
                asm volatile("s_waitcnt vmcnt(0)" ::: "memory");
                CVT_WRITE_B(nb);
                asm volatile("s_waitcnt lgkmcnt(0)" ::: "memory");
            }
        } else {
            const float wsc = *(const float*)(smem + 155648 + u * 4);
            const int abase = cur * 32768;
            const int bbase = 98304 + cur * 16384;
            const int sbuf = (u >> 2) & 1;

            // ---- frag reads (buf cur) + rescale factors ----
#pragma unroll
            for (int n = 0; n < 4; ++n)
                RD_FRAG(bF[n], bbase, wcol + n * 16 + l15);
#pragma unroll
            for (int m = 0; m < 4; ++m) {
                const float4 sv = *(const float4*)(smem + 147456 + sbuf * 4096 +
                    (u & 3) * 1024 + (wrow + m * 16 + lhi * 4) * 4);
                asv[m][0] = sv.x * wsc; asv[m][1] = sv.y * wsc;
                asv[m][2] = sv.z * wsc; asv[m][3] = sv.w * wsc;
            }

            // ---- MFMA + rescale ----
#pragma unroll
            for (int m = 0; m < 4; ++m) {
                Frag aF;
                RD_FRAG(aF, abase, wrow + m * 16 + l15);
#pragma unroll
                for (int n = 0; n < 4; ++n) {
                    f32x4 blk = __builtin_amdgcn_mfma_scale_f32_16x16x128_f8f6f4(
                        aF.v, bF[n].v, z4, 0, 0, 0, 0x7F7F7F7F, 0, 0x7F7F7F7F);
                    acc[m][n] += blk * asv[m];
                }
            }
        }

        blockbar();                      // publish tile u+1; free buf cur
        cur = (cur + 1 >= 3) ? 0 : cur + 1;
    }

    // ---- epilogue (consumers): col = lane&15, row = (lane>>4)*4 + j ----
    if (!producer) {
        float* Yg = y + (size_t)g * T_ * N_;
#pragma unroll
        for (int n = 0; n < 4; ++n) {
            const int col = n0 + wcol + n * 16 + l15;
            const float bv = bias[g * N_ + col];
#pragma unroll
            for (int m = 0; m < 4; ++m) {
                const int r0 = t0 + wrow + m * 16 + lhi * 4;
#pragma unroll
                for (int j = 0; j < 4; ++j)
                    Yg[(size_t)(r0 + j) * N_ + col] = acc[m][n][j] + bv;
            }
        }
    }
}

// ---------------------------------------------------------------------------
extern "C" void kernel_launch(void* const* d_in, const int* in_sizes, int n_in,
                              void* d_out, int out_size, void* d_ws, size_t ws_size,
                              hipStream_t stream)
{
    const float* xs     = (const float*)d_in[0];
    const float* weight = (const float*)d_in[1];
    const float* scale  = (const float*)d_in[2];
    const float* bias   = (const float*)d_in[3];
    float* y = (float*)d_out;

    uint8_t* xq8  = (uint8_t*)d_ws;                      //  58,720,256 B
    float*   ascl = (float*)((char*)d_ws + 58720256);    //   1,835,008 B

    prep_kernel<<<ACT_WGS, 256, 0, stream>>>(xs, xq8, ascl);

    gemm_fp8_kernel<<<G_ * (T_ / 256) * (N_ / 128), 768, 0, stream>>>(
        xq8, weight, ascl, scale, bias, y);
}

// Round 17
// 341.200 us; speedup vs baseline: 2.4482x; 2.4482x over previous
//
#include <hip/hip_runtime.h>
#include <hip/hip_bf16.h>
#include <stdint.h>

#define G_ 8
#define T_ 1024
#define K_ 7168
#define N_ 2048
#define KB_ 56         // K/128 quant blocks
#define NB_ 16         // N/128
#define NT8_ 56        // K-tiles of 128

#define ACT_WGS  57344   // (G*T*KB)/8

typedef __attribute__((ext_vector_type(4))) float f32x4;
typedef __attribute__((ext_vector_type(8))) int   i32x8;

typedef __attribute__((address_space(3))) uint32_t lds_u32_t;
typedef const __attribute__((address_space(1))) uint32_t gbl_u32_t;

__device__ __forceinline__ void gload_lds16(const void* gsrc, const void* ldst)
{
    __builtin_amdgcn_global_load_lds(
        (gbl_u32_t*)(uintptr_t)gsrc,
        (lds_u32_t*)(uint32_t)(uintptr_t)ldst, 16, 0, 0);
}

__device__ __forceinline__ void blockbar()
{
    asm volatile("" ::: "memory");
    __builtin_amdgcn_s_barrier();
    asm volatile("" ::: "memory");
}

// ---------------------------------------------------------------------------
// Kernel 1: activation quant only (verified body, rounds 6-16).
// ---------------------------------------------------------------------------
__global__ __launch_bounds__(256) void prep_kernel(
    const float* __restrict__ xs, uint8_t* __restrict__ xq8,
    float* __restrict__ ascale)
{
    const int bid = blockIdx.x;
    const int tid = threadIdx.x;
    const int grp = (bid * 256 + tid) >> 5;
    const int l   = tid & 31;
    const size_t base = (size_t)grp * 128 + (size_t)l * 4;

    const float4 v = *(const float4*)(xs + base);
    float am = fmaxf(fmaxf(fabsf(v.x), fabsf(v.y)),
                     fmaxf(fabsf(v.z), fabsf(v.w)));
#pragma unroll
    for (int off = 1; off <= 16; off <<= 1)
        am = fmaxf(am, __shfl_xor(am, off, 64));

    const float rs = 448.0f / am;
    const float s  = am * (1.0f / 448.0f);

    int pk = __builtin_amdgcn_cvt_pk_fp8_f32(v.x * rs, v.y * rs, 0, false);
    pk     = __builtin_amdgcn_cvt_pk_fp8_f32(v.z * rs, v.w * rs, pk, true);
    *(uint32_t*)(xq8 + base) = (uint32_t)pk;

    if (l == 0) {
        const int kb = grp % KB_;
        const int t  = (grp / KB_) & (T_ - 1);
        const int g  = grp / (KB_ * T_);
        ascale[(((size_t)(g * 4 + (t >> 8))) * KB_ + kb) * 256 + (t & 255)] = s;
    }
}

// ---------------------------------------------------------------------------
// Kernel 2: producer/consumer blockwise-fp8 grouped GEMM, 256x128 tile,
//   fused weight recode WITHIN one producer interval (no cross-barrier regs).
//   768 threads, 1 block/CU. Waves 0-7: consumers (r15 body, unchanged).
//   Waves 8-11 (producers), per interval u handling tile u+2:
//     LOAD_B16(u+2) -> regs; STG_A(u+2) DMA; vmcnt(8) [drains A(u+1) with a
//     full interval of flight + B16(u+2); keeps A(u+2) in flight];
//     cvt+swizzled ds_write B(u+2) -> buf (u+2)%3; [S]; lgkmcnt(0); barrier.
//   LDS: A 3x32K @0 | B 3x16K @98304 | ascale 2x4K @147456 | ws @155648.
// ---------------------------------------------------------------------------
union Frag { i32x8 v; struct { int4 lo, hi; } p; };

#define RD_FRAG(dst, base, r)                                                 \
  { const int rx_ = ((r) & 7) << 4;                                           \
    const char* bp_ = smem + (base) + (r)*128;                                \
    dst.p.lo = *(const int4*)(bp_ + ((lhi*32) ^ rx_));                        \
    dst.p.hi = *(const int4*)(bp_ + ((lhi*32 + 16) ^ rx_)); }

#define STG_A(c, t, bb) gload_lds16(pA8[c] + (size_t)(t)*128,                 \
      smem + (bb)*32768 + (c)*4096 + ptid*16)
#define STG_S(c) gload_lds16(pS + (size_t)(c)*1024,                           \
      smem + 147456 + ((c)&1)*4096 + ptid*16)

// 16 coalesced dwordx4 loads of fp32 codes for B k-tile t
#define LOAD_B16(t)                                                           \
  { _Pragma("unroll") for (int q = 0; q < 16; ++q)                            \
      br[q] = *(const f32x4*)(pWf + (size_t)q * 8 * K_ + (size_t)(t) * 128); }

// convert + swizzled ds_write_b32 into B buf bb (verified mapping, r16)
#define CVT_WRITE_B(bb)                                                       \
  { _Pragma("unroll") for (int q = 0; q < 16; ++q) {                          \
      int pk_ = __builtin_amdgcn_cvt_pk_fp8_f32(br[q][0], br[q][1], 0, false);\
      pk_ = __builtin_amdgcn_cvt_pk_fp8_f32(br[q][2], br[q][3], pk_, true);   \
      const int r_ = q * 8 + (ptid >> 5);                                     \
      *(uint32_t*)(smem + 98304 + (bb)*16384 + r_*128 +                       \
          ((((ptid & 31) >> 2) ^ (r_ & 7)) << 4) + (ptid & 3) * 4) =          \
          (uint32_t)pk_;                                                      \
  } }

__global__ __launch_bounds__(768, 1) void gemm_fp8_kernel(
    const uint8_t* __restrict__ xq8, const float* __restrict__ w,
    const float* __restrict__ ascale, const float* __restrict__ wscale,
    const float* __restrict__ bias, float* __restrict__ y)
{
    __shared__ char smem[155904];

    const int bx0 = blockIdx.x;          // 0..511
    const int g     = bx0 & 7;           // group == XCD
    const int inner = bx0 >> 3;          // 0..63
    const int tm    = inner & 3;         // 0..3 (256-row tiles)
    const int tn    = inner >> 2;        // 0..15
    const int t0 = tm * 256, n0 = tn * 128;

    const int tid  = threadIdx.x, lane = tid & 63, wid = tid >> 6;
    const bool producer = (wid >= 8);
    const int ptid = tid & 255;          // producer-local 0..255
    const int l15 = lane & 15, lhi = lane >> 4;
    const int wrow = (wid >> 1) * 64;    // consumer rows (wid 0..7)
    const int wcol = (wid & 1) * 64;

    const uint8_t* Ag = xq8 + (size_t)g * T_ * K_;
    const float*   Wg = w   + (size_t)g * N_ * K_;

    // A staging map: LDS(row = c*32 + ptid/8, slot = ptid&7) <- global
    // slot ^ (row&7)
    const int srow = ptid >> 3;
    const int xoff = ((ptid & 7) ^ (srow & 7)) * 16;
    const uint8_t* pA8[8];
#pragma unroll
    for (int c = 0; c < 8; ++c)
        pA8[c] = Ag + (size_t)(t0 + c * 32 + srow) * K_ + xoff;

    // B fp32 source: load q covers row q*8 + (ptid>>5), cols (ptid&31)*4..
    const float* pWf = Wg + (size_t)(n0 + (ptid >> 5)) * K_ + (ptid & 31) * 4;

    // ascale: [g][tb][kb][256], tb == tm; chunk = 4 kb = 4KB
    const float* pS = ascale + ((size_t)(g * 4 + tm) * KB_) * 256 + ptid * 4;

    const f32x4 z4 = {0.f, 0.f, 0.f, 0.f};
    f32x4 acc[4][4] = {};
    Frag bF[4];
    f32x4 asv[4];

    // ---- prologue: tiles 0,1 (B via in-interval reg-cvt), S0, wscale ----
    if (producer) {
        f32x4 br[16];
        if (ptid < KB_) {
            const float wv = wscale[((size_t)(g * NB_ + tn)) * KB_ + ptid];
            *(float*)(smem + 155648 + ptid * 4) = wv;
        }
        STG_S(0);
        LOAD_B16(0);
#pragma unroll
        for (int c = 0; c < 8; ++c) STG_A(c, 0, 0);
        asm volatile("s_waitcnt vmcnt(8)" ::: "memory");  // S0+B16(0) landed
        CVT_WRITE_B(0);
        LOAD_B16(1);
#pragma unroll
        for (int c = 0; c < 8; ++c) STG_A(c, 1, 1);
        asm volatile("s_waitcnt vmcnt(8)" ::: "memory");  // A8(0)+B16(1) landed
        CVT_WRITE_B(1);
        asm volatile("s_waitcnt lgkmcnt(0)" ::: "memory");
    } else {
        __builtin_amdgcn_s_setprio(1);   // consumers keep MFMA priority
    }
    blockbar();
    // loop entry invariant: outstanding = A8(u+1) (8 newest)

    int cur = 0;
    for (int u = 0; u < NT8_; ++u) {
        if (producer) {
            if (u + 2 < NT8_) {
                const int fb = (cur + 2 >= 3) ? cur - 1 : cur + 2;   // (u+2)%3
                f32x4 br[16];
                LOAD_B16(u + 2);
#pragma unroll
                for (int c = 0; c < 8; ++c) STG_A(c, u + 2, fb);
                // keep A8(u+2) in flight; drain A8(u+1) + B16(u+2) [+S]
                asm volatile("s_waitcnt vmcnt(8)" ::: "memory");
                CVT_WRITE_B(fb);
                if ((u & 3) == 0 && u + 4 < NT8_) STG_S((u >> 2) + 1);
                asm volatile("s_waitcnt lgkmcnt(0)" ::: "memory");
            } else if (u + 1 < NT8_) {
                asm volatile("s_waitcnt vmcnt(0)" ::: "memory"); // A8(NT-1)
            }
        } else {
            const float wsc = *(const float*)(smem + 155648 + u * 4);
            const int abase = cur * 32768;
            const int bbase = 98304 + cur * 16384;
            const int sbuf = (u >> 2) & 1;

            // ---- frag reads (buf cur) + rescale factors ----
#pragma unroll
            for (int n = 0; n < 4; ++n)
                RD_FRAG(bF[n], bbase, wcol + n * 16 + l15);
#pragma unroll
            for (int m = 0; m < 4; ++m) {
                const float4 sv = *(const float4*)(smem + 147456 + sbuf * 4096 +
                    (u & 3) * 1024 + (wrow + m * 16 + lhi * 4) * 4);
                asv[m][0] = sv.x * wsc; asv[m][1] = sv.y * wsc;
                asv[m][2] = sv.z * wsc; asv[m][3] = sv.w * wsc;
            }

            // ---- MFMA + rescale ----
#pragma unroll
            for (int m = 0; m < 4; ++m) {
                Frag aF;
                RD_FRAG(aF, abase, wrow + m * 16 + l15);
#pragma unroll
                for (int n = 0; n < 4; ++n) {
                    f32x4 blk = __builtin_amdgcn_mfma_scale_f32_16x16x128_f8f6f4(
                        aF.v, bF[n].v, z4, 0, 0, 0, 0x7F7F7F7F, 0, 0x7F7F7F7F);
                    acc[m][n] += blk * asv[m];
                }
            }
        }

        blockbar();                      // publish tile u+1; free buf cur
        cur = (cur + 1 >= 3) ? 0 : cur + 1;
    }

    // ---- epilogue (consumers): col = lane&15, row = (lane>>4)*4 + j ----
    if (!producer) {
        float* Yg = y + (size_t)g * T_ * N_;
#pragma unroll
        for (int n = 0; n < 4; ++n) {
            const int col = n0 + wcol + n * 16 + l15;
            const float bv = bias[g * N_ + col];
#pragma unroll
            for (int m = 0; m < 4; ++m) {
                const int r0 = t0 + wrow + m * 16 + lhi * 4;
#pragma unroll
                for (int j = 0; j < 4; ++j)
                    Yg[(size_t)(r0 + j) * N_ + col] = acc[m][n][j] + bv;
            }
        }
    }
}

// ---------------------------------------------------------------------------
extern "C" void kernel_launch(void* const* d_in, const int* in_sizes, int n_in,
                              void* d_out, int out_size, void* d_ws, size_t ws_size,
                              hipStream_t stream)
{
    const float* xs     = (const float*)d_in[0];
    const float* weight = (const float*)d_in[1];
    const float* scale  = (const float*)d_in[2];
    const float* bias   = (const float*)d_in[3];
    float* y = (float*)d_out;

    uint8_t* xq8  = (uint8_t*)d_ws;                      //  58,720,256 B
    float*   ascl = (float*)((char*)d_ws + 58720256);    //   1,835,008 B

    prep_kernel<<<ACT_WGS, 256, 0, stream>>>(xs, xq8, ascl);

    gemm_fp8_kernel<<<G_ * (T_ / 256) * (N_ / 128), 768, 0, stream>>>(
        xq8, weight, ascl, scale, bias, y);
}